// Round 2
// baseline (1935.533 us; speedup 1.0000x reference)
//
#include <hip/hip_runtime.h>

// RNN_73701638799445: 2-layer tanh RNN, persistent-kernel recurrence.
//   preps:     gather x->bf16; W0->bf16; Wh0/W1/Wh1 -> hi/lo B-operand "panels";
//              Wd->bf16 padded; initial hidden -> A-operand-layout state bufs.
//   U0 GEMM:   U0[4096,1024] = Xbf @ W0^T + b0          (bf16 MFMA, 128x128)
//   persist:   ONE kernel, 96 blocks (co-resident, <=256 CUs), 65 phases with a
//              hand-rolled device-scope grid barrier. Phase t: 32 L0 blocks do
//              h0(t)=tanh(U0[t]+h0(t-1)@Wh0^T); 64 L1 blocks do
//              h1(t-1)=tanh(h0(t-1)@W1^T+h1(t-2)@Wh1^T+b1). Weights hi/lo bf16
//              (near-fp32 accuracy), streamed global->LDS (global_load_lds,
//              double-buffered); state read as MFMA A-fragments straight from
//              global in fragment-friendly chunk layout. Weight slices pin to
//              each block's XCD L2 across phases (no HBM re-reads).
//   decoder:   logits[4096,10000] = H1bf @ Wd^T + bd    (bf16 MFMA)

#define S_LEN 64
#define BATCH 64
#define HID   1024
#define VOCAB 10000
#define VPAD  10112           // 79 * 128
#define SB    4096
#define SBV   40960000        // SB * VOCAB
#define NBLK  96              // persistent blocks: 32 layer0 + 64 layer1

typedef __attribute__((ext_vector_type(4))) float  f32x4;
typedef __attribute__((ext_vector_type(8))) __bf16 bf16x8;

__device__ inline unsigned short f2bf(float x) {
  union { float f; unsigned int u; } v; v.f = x;
  unsigned int r = v.u + 0x7fffu + ((v.u >> 16) & 1u);   // RNE
  return (unsigned short)(r >> 16);
}
__device__ inline float bf2f(unsigned short s) {
  union { unsigned int u; float f; } v; v.u = ((unsigned int)s) << 16;
  return v.f;
}

// ---------------- prep kernels ----------------

__global__ __launch_bounds__(256) void prep_x(
    const int* __restrict__ inputs, const float* __restrict__ emb,
    unsigned short* __restrict__ Xbf) {
  int i = blockIdx.x * 256 + threadIdx.x;       // SB*HID/4 threads
  int row = i >> 8;
  int c4  = (i & 255) * 4;
  int tok = inputs[row];
  const float4 v = *reinterpret_cast<const float4*>(emb + (size_t)tok * HID + c4);
  unsigned short* o = Xbf + (size_t)row * HID + c4;
  o[0] = f2bf(v.x); o[1] = f2bf(v.y); o[2] = f2bf(v.z); o[3] = f2bf(v.w);
}

// Panels: P[(k/8)*1024 + n] is a 16B chunk = W[n][k..k+8) (hi or lo bf16).
__global__ __launch_bounds__(256) void prep_panels(
    const float* __restrict__ W0, const float* __restrict__ Wh0,
    const float* __restrict__ W1, const float* __restrict__ Wh1,
    unsigned short* __restrict__ W0bf,
    unsigned short* __restrict__ PWh0h, unsigned short* __restrict__ PWh0l,
    unsigned short* __restrict__ PW1h,  unsigned short* __restrict__ PW1l,
    unsigned short* __restrict__ PWh1h, unsigned short* __restrict__ PWh1l) {
  int id = blockIdx.x * 256 + threadIdx.x;      // HID*128 threads
  int n = id >> 7, kc = id & 127;
  size_t src = (size_t)n * HID + kc * 8;
  size_t dst = ((size_t)kc * HID + n) * 8;
#pragma unroll
  for (int j = 0; j < 8; ++j) W0bf[src + j] = f2bf(W0[src + j]);
  {
    unsigned short hi[8], lo[8];
#pragma unroll
    for (int j = 0; j < 8; ++j) {
      float w = Wh0[src + j]; hi[j] = f2bf(w); lo[j] = f2bf(w - bf2f(hi[j]));
    }
#pragma unroll
    for (int j = 0; j < 8; ++j) { PWh0h[dst + j] = hi[j]; PWh0l[dst + j] = lo[j]; }
  }
  {
    unsigned short hi[8], lo[8];
#pragma unroll
    for (int j = 0; j < 8; ++j) {
      float w = W1[src + j]; hi[j] = f2bf(w); lo[j] = f2bf(w - bf2f(hi[j]));
    }
#pragma unroll
    for (int j = 0; j < 8; ++j) { PW1h[dst + j] = hi[j]; PW1l[dst + j] = lo[j]; }
  }
  {
    unsigned short hi[8], lo[8];
#pragma unroll
    for (int j = 0; j < 8; ++j) {
      float w = Wh1[src + j]; hi[j] = f2bf(w); lo[j] = f2bf(w - bf2f(hi[j]));
    }
#pragma unroll
    for (int j = 0; j < 8; ++j) { PWh1h[dst + j] = hi[j]; PWh1l[dst + j] = lo[j]; }
  }
}

__global__ __launch_bounds__(256) void prep_wd(
    const float* __restrict__ Wd, const float* __restrict__ bd,
    unsigned short* __restrict__ Wdbf, float* __restrict__ bdp) {
  int id = blockIdx.x * 256 + threadIdx.x;      // VPAD*HID threads
  int row = id >> 10;
  Wdbf[id] = (row < VOCAB) ? f2bf(Wd[id]) : (unsigned short)0;
  if (id < VPAD) bdp[id] = (id < VOCAB) ? bd[id] : 0.0f;
}

// State layout: chunk (k/8)*64 + m is 16B = h[m][k..k+8) as bf16 (hi).
__global__ __launch_bounds__(256) void prep_state(
    const float* __restrict__ hidden,
    unsigned short* __restrict__ A0, unsigned short* __restrict__ A1) {
  int id = blockIdx.x * 256 + threadIdx.x;      // BATCH*128 threads
  int m = id >> 7, hc = id & 127;
  size_t src = (size_t)m * HID + hc * 8;
  size_t dst = ((size_t)hc * 64 + m) * 8;
#pragma unroll
  for (int j = 0; j < 8; ++j) A0[dst + j] = f2bf(hidden[src + j]);
#pragma unroll
  for (int j = 0; j < 8; ++j) A1[dst + j] = f2bf(hidden[(size_t)BATCH * HID + src + j]);
}

__global__ void bar_init(unsigned* bar) {
  if (threadIdx.x < 32) bar[threadIdx.x] = 0u;
}

// ---------------- big bf16 GEMM (A row-major [M,K], B row-major [Npad,K]) ----------------
__global__ __launch_bounds__(256) void gemm_bt_bias(
    const unsigned short* __restrict__ A, const unsigned short* __restrict__ B,
    const float* __restrict__ bias, float* __restrict__ C,
    int K, int N, int ldc) {
  const int m0 = blockIdx.y * 128;
  const int n0 = blockIdx.x * 128;
  __shared__ __align__(16) unsigned short As[128 * 64];
  __shared__ __align__(16) unsigned short Bsm[128 * 64];
  const int tid = threadIdx.x;
  const int lane = tid & 63, w = tid >> 6;
  const int wm = w >> 1, wn = w & 1;
  f32x4 acc[4][4] = {};
  for (int k0 = 0; k0 < K; k0 += 64) {
#pragma unroll
    for (int i = 0; i < 4; ++i) {
      int off = i * 256 + tid;
      int row = off >> 3;
      int c8  = off & 7;
      __builtin_amdgcn_global_load_lds(
          (const __attribute__((address_space(1))) unsigned int*)(const void*)
              (A + (size_t)(m0 + row) * K + k0 + c8 * 8),
          (__attribute__((address_space(3))) unsigned int*)(void*)(As + (size_t)off * 8),
          16, 0, 0);
      __builtin_amdgcn_global_load_lds(
          (const __attribute__((address_space(1))) unsigned int*)(const void*)
              (B + (size_t)(n0 + row) * K + k0 + c8 * 8),
          (__attribute__((address_space(3))) unsigned int*)(void*)(Bsm + (size_t)off * 8),
          16, 0, 0);
    }
    __syncthreads();
#pragma unroll
    for (int kk = 0; kk < 64; kk += 32) {
      bf16x8 af[4], bfr[4];
#pragma unroll
      for (int f = 0; f < 4; ++f) {
        int ar = wm * 64 + f * 16 + (lane & 15);
        int ac = kk + (lane >> 4) * 8;
        af[f]  = *reinterpret_cast<const bf16x8*>(&As[ar * 64 + ac]);
        int br = wn * 64 + f * 16 + (lane & 15);
        bfr[f] = *reinterpret_cast<const bf16x8*>(&Bsm[br * 64 + ac]);
      }
#pragma unroll
      for (int i = 0; i < 4; ++i)
#pragma unroll
        for (int j = 0; j < 4; ++j)
          acc[i][j] = __builtin_amdgcn_mfma_f32_16x16x32_bf16(af[i], bfr[j], acc[i][j], 0, 0, 0);
    }
    __syncthreads();
  }
  const int rbase = (lane >> 4) * 4;
  const int cbase = lane & 15;
#pragma unroll
  for (int i = 0; i < 4; ++i) {
#pragma unroll
    for (int j = 0; j < 4; ++j) {
      int col = n0 + wn * 64 + j * 16 + cbase;
      if (col < N) {
        float bv = bias[col];
#pragma unroll
        for (int r = 0; r < 4; ++r) {
          int row = m0 + wm * 64 + i * 16 + rbase + r;
          C[(size_t)row * ldc + col] = acc[i][j][r] + bv;
        }
      }
    }
  }
}

// ---------------- grid barrier (device scope, sense via generation) ----------------
__device__ inline void gbar(unsigned* bar, unsigned* lgen) {
  __syncthreads();                      // drains each wave's vmcnt before barrier
  if (threadIdx.x == 0) {
    __threadfence();                    // release: writeback to device scope
    unsigned arrived = atomicAdd(bar, 1u);
    if (arrived == NBLK - 1) {
      __threadfence();
      __hip_atomic_store(bar, 0u, __ATOMIC_RELAXED, __HIP_MEMORY_SCOPE_AGENT);
      __hip_atomic_fetch_add(bar + 16, 1u, __ATOMIC_RELEASE, __HIP_MEMORY_SCOPE_AGENT);
    } else {
      unsigned target = *lgen + 1;
      while (__hip_atomic_load(bar + 16, __ATOMIC_ACQUIRE, __HIP_MEMORY_SCOPE_AGENT) < target) {
        __builtin_amdgcn_s_sleep(1);
      }
    }
    *lgen += 1;
    __threadfence();                    // acquire: invalidate stale cached lines
  }
  __syncthreads();
}

// ---------------- persistent recurrence kernel ----------------
__global__ __launch_bounds__(256, 1) void rnn_persist(
    const float* __restrict__ U0, const float* __restrict__ b1v,
    const unsigned short* __restrict__ PWh0h, const unsigned short* __restrict__ PWh0l,
    const unsigned short* __restrict__ PW1h,  const unsigned short* __restrict__ PW1l,
    const unsigned short* __restrict__ PWh1h, const unsigned short* __restrict__ PWh1l,
    unsigned short* __restrict__ A0a, unsigned short* __restrict__ A0b,
    unsigned short* __restrict__ A1a, unsigned short* __restrict__ A1b,
    unsigned short* __restrict__ H1, float* __restrict__ hid0, float* __restrict__ hid1,
    unsigned* __restrict__ bar) {
  const int bid = blockIdx.x, tid = threadIdx.x;
  const int lane = tid & 63, w = tid >> 6;
  unsigned lgen = 0;
  unsigned short* A0buf[2] = {A0a, A0b};
  unsigned short* A1buf[2] = {A1a, A1b};
  __shared__ __align__(16) unsigned short Bs[2][8192];   // 2 x 16KB weight stage
  __shared__ __align__(16) float hb[2048];               // 32x64 f32 bounce

  if (bid < 32) {
    // ---------- layer0: h0(t) = tanh(U0[t] + h0(t-1) @ Wh0^T), cols [n0,n0+32) ----------
    const int n0 = bid * 32;
    const int m0 = w * 16;
    for (int t = 0; t < 65; ++t) {
      if (t < 64) {
        const unsigned short* Acur = A0buf[t & 1];
        f32x4 acc0 = {0.f,0.f,0.f,0.f}, acc1 = {0.f,0.f,0.f,0.f};
        // stage super s (k-span 128, hi+lo) into Bs[d]: 1024 chunks of 16B
        auto stage = [&](int s, int d) {
#pragma unroll
          for (int j = 0; j < 4; ++j) {
            int idx = j * 256 + tid;
            int half = idx >> 9, kcl = (idx >> 5) & 15, nl = idx & 31;
            const unsigned short* P = half ? PWh0l : PWh0h;
            __builtin_amdgcn_global_load_lds(
                (const __attribute__((address_space(1))) unsigned int*)(const void*)
                    (P + ((size_t)(s * 16 + kcl) * HID + n0 + nl) * 8),
                (__attribute__((address_space(3))) unsigned int*)(void*)(&Bs[d][(size_t)idx * 8]),
                16, 0, 0);
          }
        };
        stage(0, 0);
        __syncthreads();
        for (int s = 0; s < 8; ++s) {
          if (s < 7) stage(s + 1, (s + 1) & 1);
          const unsigned short* B = Bs[s & 1];
#pragma unroll
          for (int ksl = 0; ksl < 4; ++ksl) {
            int kch = (s * 4 + ksl) * 4 + (lane >> 4);
            bf16x8 a = *reinterpret_cast<const bf16x8*>(
                Acur + ((size_t)kch * 64 + m0 + (lane & 15)) * 8);
            int rb = ksl * 4 + (lane >> 4);
            bf16x8 bh0 = *reinterpret_cast<const bf16x8*>(&B[((size_t)(rb * 32 + (lane & 15))) * 8]);
            bf16x8 bh1 = *reinterpret_cast<const bf16x8*>(&B[((size_t)(rb * 32 + 16 + (lane & 15))) * 8]);
            bf16x8 bl0 = *reinterpret_cast<const bf16x8*>(&B[((size_t)((16 + rb) * 32 + (lane & 15))) * 8]);
            bf16x8 bl1 = *reinterpret_cast<const bf16x8*>(&B[((size_t)((16 + rb) * 32 + 16 + (lane & 15))) * 8]);
            acc0 = __builtin_amdgcn_mfma_f32_16x16x32_bf16(a, bh0, acc0, 0, 0, 0);
            acc0 = __builtin_amdgcn_mfma_f32_16x16x32_bf16(a, bl0, acc0, 0, 0, 0);
            acc1 = __builtin_amdgcn_mfma_f32_16x16x32_bf16(a, bh1, acc1, 0, 0, 0);
            acc1 = __builtin_amdgcn_mfma_f32_16x16x32_bf16(a, bl1, acc1, 0, 0, 0);
          }
          __syncthreads();
        }
        // epilogue: bounce acc -> [col_local][m], then add U0, tanh, pack
        {
          int cb = lane & 15, rb = (lane >> 4) * 4;
#pragma unroll
          for (int r = 0; r < 4; ++r) {
            hb[cb * 64 + m0 + rb + r]        = acc0[r];
            hb[(16 + cb) * 64 + m0 + rb + r] = acc1[r];
          }
        }
        __syncthreads();
        {
          int cc = tid >> 6, m = tid & 63;
          const float* u0r = U0 + ((size_t)t * 64 + m) * HID + n0 + cc * 8;
          float h[8];
          union { unsigned short u[8]; uint4 v; } pk;
#pragma unroll
          for (int j = 0; j < 8; ++j) {
            h[j] = tanhf(hb[(cc * 8 + j) * 64 + m] + u0r[j]);
            pk.u[j] = f2bf(h[j]);
          }
          *reinterpret_cast<uint4*>(A0buf[(t + 1) & 1] + ((size_t)(n0 / 8 + cc) * 64 + m) * 8) = pk.v;
          if (t == 63) {
            float* o = hid0 + (size_t)m * HID + n0 + cc * 8;
#pragma unroll
            for (int j = 0; j < 8; ++j) o[j] = h[j];
          }
        }
      }
      if (t < 64) gbar(bar, &lgen);
    }
  } else {
    // ---------- layer1: h1(t-1) = tanh(h0(t-1)@W1^T + h1(t-2)@Wh1^T + b1), cols [n0,n0+16) ----------
    const int g = bid - 32;
    const int n0 = g * 16;
    const int m0 = w * 16;
    for (int t = 0; t < 65; ++t) {
      if (t > 0) {
        const unsigned short* Ah0 = A0buf[t & 1];
        const unsigned short* Ah1 = A1buf[(t + 1) & 1];
        f32x4 acc = {0.f,0.f,0.f,0.f};
        auto stage = [&](int sup, int d) {
          int part = sup >> 3, sl = sup & 7;
          const unsigned short* Ph = part ? PWh1h : PW1h;
          const unsigned short* Pl = part ? PWh1l : PW1l;
#pragma unroll
          for (int j = 0; j < 2; ++j) {
            int idx = j * 256 + tid;
            int half = idx >> 8, kcl = (idx >> 4) & 15, nl = idx & 15;
            const unsigned short* P = half ? Pl : Ph;
            __builtin_amdgcn_global_load_lds(
                (const __attribute__((address_space(1))) unsigned int*)(const void*)
                    (P + ((size_t)(sl * 16 + kcl) * HID + n0 + nl) * 8),
                (__attribute__((address_space(3))) unsigned int*)(void*)(&Bs[d][(size_t)idx * 8]),
                16, 0, 0);
          }
        };
        stage(0, 0);
        __syncthreads();
        for (int sup = 0; sup < 16; ++sup) {
          if (sup < 15) stage(sup + 1, (sup + 1) & 1);
          const unsigned short* B = Bs[sup & 1];
          const unsigned short* Acur = (sup < 8) ? Ah0 : Ah1;
          int sl = sup & 7;
#pragma unroll
          for (int ksl = 0; ksl < 4; ++ksl) {
            int kch = (sl * 4 + ksl) * 4 + (lane >> 4);
            bf16x8 a = *reinterpret_cast<const bf16x8*>(
                Acur + ((size_t)kch * 64 + m0 + (lane & 15)) * 8);
            int rb = ksl * 4 + (lane >> 4);
            bf16x8 bh = *reinterpret_cast<const bf16x8*>(&B[((size_t)(rb * 16 + (lane & 15))) * 8]);
            bf16x8 bl = *reinterpret_cast<const bf16x8*>(&B[((size_t)((16 + rb) * 16 + (lane & 15))) * 8]);
            acc = __builtin_amdgcn_mfma_f32_16x16x32_bf16(a, bh, acc, 0, 0, 0);
            acc = __builtin_amdgcn_mfma_f32_16x16x32_bf16(a, bl, acc, 0, 0, 0);
          }
          __syncthreads();
        }
        {
          int cb = lane & 15, rb = (lane >> 4) * 4;
#pragma unroll
          for (int r = 0; r < 4; ++r) hb[cb * 64 + m0 + rb + r] = acc[r];
        }
        __syncthreads();
        if (tid < 128) {
          int cc = tid >> 6, m = tid & 63;
          float h[8];
          union { unsigned short u[8]; uint4 v; } pk;
#pragma unroll
          for (int j = 0; j < 8; ++j) {
            h[j] = tanhf(hb[(cc * 8 + j) * 64 + m] + b1v[n0 + cc * 8 + j]);
            pk.u[j] = f2bf(h[j]);
          }
          *reinterpret_cast<uint4*>(A1buf[t & 1] + ((size_t)(n0 / 8 + cc) * 64 + m) * 8) = pk.v;
          *reinterpret_cast<uint4*>(H1 + ((size_t)(t - 1) * 64 + m) * HID + n0 + cc * 8) = pk.v;
          if (t == 64) {
            float* o = hid1 + (size_t)m * HID + n0 + cc * 8;
#pragma unroll
            for (int j = 0; j < 8; ++j) o[j] = h[j];
          }
        }
      }
      if (t < 64) gbar(bar, &lgen);
    }
  }
}

// ---------------- launcher ----------------

extern "C" void kernel_launch(void* const* d_in, const int* in_sizes, int n_in,
                              void* d_out, int out_size, void* d_ws, size_t ws_size,
                              hipStream_t stream) {
  (void)in_sizes; (void)n_in; (void)out_size; (void)ws_size;
  const int*   inputs = (const int*)  d_in[0];
  const float* hidden = (const float*)d_in[1];
  const float* emb    = (const float*)d_in[2];
  const float* W0     = (const float*)d_in[3];
  const float* Wh0    = (const float*)d_in[4];
  const float* b0     = (const float*)d_in[5];
  const float* W1     = (const float*)d_in[6];
  const float* Wh1    = (const float*)d_in[7];
  const float* b1     = (const float*)d_in[8];
  const float* Wd     = (const float*)d_in[9];
  const float* bd     = (const float*)d_in[10];

  // scratch inside d_out (consumed before the decoder overwrites logits)
  float*          U0  = (float*)d_out;                                       // 16MB
  unsigned short* Xbf = (unsigned short*)((char*)d_out + (size_t)16777216);  // 8MB

  // persistent scratch in d_ws
  char* ws = (char*)d_ws;
  size_t off = 0;
  auto alloc = [&](size_t bytes) { size_t p = off; off = (off + bytes + 255) & ~(size_t)255; return p; };
  unsigned short* W0bf  = (unsigned short*)(ws + alloc((size_t)HID * HID * 2));
  unsigned short* Wdbf  = (unsigned short*)(ws + alloc((size_t)VPAD * HID * 2));
  float*          bdp   = (float*)         (ws + alloc((size_t)VPAD * 4));
  unsigned short* PWh0h = (unsigned short*)(ws + alloc((size_t)HID * HID * 2));
  unsigned short* PWh0l = (unsigned short*)(ws + alloc((size_t)HID * HID * 2));
  unsigned short* PW1h  = (unsigned short*)(ws + alloc((size_t)HID * HID * 2));
  unsigned short* PW1l  = (unsigned short*)(ws + alloc((size_t)HID * HID * 2));
  unsigned short* PWh1h = (unsigned short*)(ws + alloc((size_t)HID * HID * 2));
  unsigned short* PWh1l = (unsigned short*)(ws + alloc((size_t)HID * HID * 2));
  unsigned short* H1bf  = (unsigned short*)(ws + alloc((size_t)SB * HID * 2));
  unsigned short* A0s[2], *A1s[2];
  A0s[0] = (unsigned short*)(ws + alloc((size_t)BATCH * HID * 2));
  A0s[1] = (unsigned short*)(ws + alloc((size_t)BATCH * HID * 2));
  A1s[0] = (unsigned short*)(ws + alloc((size_t)BATCH * HID * 2));
  A1s[1] = (unsigned short*)(ws + alloc((size_t)BATCH * HID * 2));
  unsigned*       bar   = (unsigned*)(ws + alloc(256));

  float* hid0 = (float*)d_out + (size_t)SBV;            // final h0 [B,H]
  float* hid1 = hid0 + (size_t)BATCH * HID;             // final h1 [B,H]

  // prep
  prep_x     <<<SB * HID / 4 / 256, 256, 0, stream>>>(inputs, emb, Xbf);
  prep_panels<<<HID * 128 / 256,    256, 0, stream>>>(W0, Wh0, W1, Wh1, W0bf,
                                                      PWh0h, PWh0l, PW1h, PW1l, PWh1h, PWh1l);
  prep_wd    <<<VPAD * HID / 256,   256, 0, stream>>>(Wd, bd, Wdbf, bdp);
  prep_state <<<BATCH * 128 / 256,  256, 0, stream>>>(hidden, A0s[0], A1s[0]);
  bar_init   <<<1, 64, 0, stream>>>(bar);

  // U0 = X @ W0^T + b0
  gemm_bt_bias<<<dim3(HID / 128, SB / 128), 256, 0, stream>>>(
      Xbf, W0bf, b0, U0, HID, HID, HID);

  // persistent recurrence: 65 phases, 64 internal grid barriers
  rnn_persist<<<NBLK, 256, 0, stream>>>(
      U0, b1, PWh0h, PWh0l, PW1h, PW1l, PWh1h, PWh1l,
      A0s[0], A0s[1], A1s[0], A1s[1], H1bf, hid0, hid1, bar);

  // logits = H1 @ Wd^T + bd
  gemm_bt_bias<<<dim3(VPAD / 128, SB / 128), 256, 0, stream>>>(
      H1bf, Wdbf, bdp, (float*)d_out, HID, VOCAB, VOCAB);
}